// Round 5
// baseline (7525.112 us; speedup 1.0000x reference)
//
#include <hip/hip_runtime.h>
#include <cmath>

// CfC encoder, persistent kernel with contention-free scoreboard grid barrier.
// Plain launch (graph-capture-safe); 256 blocks on 256 CUs -> all resident.
// Weights live in VGPRs (loaded+masked+fp16-converted once at startup).
// Roles by blockIdx: [0,128)   XG: split x(t+2) -> fp16 planes, then x-part GEMM (t+1)
//                    [128,192) R0: L0 recurrent GEMM + epilogue (t)
//                    [192,256) R1: L1 (t-1) + L2 (t-2, writes out at t=63)
// Block = 4 waves = 4 gates (ff1,ff2,ta,tb); epilogue combines gates via LDS.
//
// Barrier layout (uint, 64B-strided to kill false sharing):
//   slot[i]  at bar[i*16],        i in [0,256)   — per-block arrival, store-only
//   flag[g]  at bar[4096 + g*16], g in [0,16)    — replicated release flags
// Block 0 wave 0 sweeps slots (acquire), then stores all 16 flags (release).
// Block b polls flag[b>>4] only (16 pollers/line). No atomic RMW anywhere.

typedef __attribute__((ext_vector_type(8))) _Float16 half8;
typedef __attribute__((ext_vector_type(4))) float f32x4;

#define DEVINL __device__ __forceinline__

DEVINL f32x4 MF(half8 a, half8 b, f32x4 c) {
  return __builtin_amdgcn_mfma_f32_16x16x32_f16(a, b, c, 0, 0, 0);
}

DEVINL void gridbar(unsigned* bar, unsigned k) {
  __syncthreads();                       // block done with prior step's work
  if (blockIdx.x == 0) {
    if (threadIdx.x < 64) {
      const int i0 = threadIdx.x * 4;    // this lane owns slots i0..i0+3
      for (;;) {
        bool ok = true;
#pragma unroll
        for (int j = 0; j < 4; ++j) {
          const int idx = i0 + j;
          if (idx != 0) {                // slot 0 = self, trivially arrived
            unsigned v = __hip_atomic_load(bar + idx * 16, __ATOMIC_ACQUIRE,
                                           __HIP_MEMORY_SCOPE_AGENT);
            ok &= (v >= k);
          }
        }
        if (__ballot(ok) == ~0ull) break;
        __builtin_amdgcn_s_sleep(2);
      }
      if (threadIdx.x < 16)
        __hip_atomic_store(bar + 4096 + threadIdx.x * 16, k, __ATOMIC_RELEASE,
                           __HIP_MEMORY_SCOPE_AGENT);
    }
  } else {
    if (threadIdx.x == 0) {
      __hip_atomic_store(bar + blockIdx.x * 16, k, __ATOMIC_RELEASE,
                         __HIP_MEMORY_SCOPE_AGENT);
      const unsigned g = blockIdx.x >> 4;
      while (__hip_atomic_load(bar + 4096 + g * 16, __ATOMIC_ACQUIRE,
                               __HIP_MEMORY_SCOPE_AGENT) < k)
        __builtin_amdgcn_s_sleep(4);
    }
  }
  __syncthreads();                       // fan the release out to all waves
}

struct Params {
  const float *base, *visual;
  const float *w0f1, *w0f2, *w0ta, *w0tb, *m0;
  const float *b0f1, *b0f2, *b0ta, *b0tb;
  const float *w1f1, *w1f2, *w1ta, *w1tb, *m1;
  const float *b1f1, *b1f2, *b1ta, *b1tb;
  const float *w2f1, *w2f2, *w2ta, *w2tb, *m2;
  const float *b2f1, *b2f2, *b2ta, *b2tb;
  _Float16 *xh0, *xl0, *xh1, *xl1;        // x split planes, 512*768, buf = t&1
  float *xacc0, *xacc1;                   // x pre-GEMM out, 512*2048 fp32, buf = t&1
  _Float16 *h0h0, *h0h1, *h0l0, *h0l1;    // h(t) lives in buf t&1
  _Float16 *h1h0, *h1h1, *h1l0, *h1l1;
  _Float16 *h2h0, *h2h1, *h2l0, *h2l1;
  unsigned *hz; int hzN;                  // h region to zero at startup
  unsigned *bar;                          // barrier scoreboard (pre-zeroed)
  float *out;
};

// Load one wave's B slice: rows = 16 neurons (lane&15), cols = K-range,
// from fp32 weights (+optional mask), converted to fp16, into VGPRs.
template <int NC>
DEVINL void load_b(const float* w, const float* mask, int Kfull, int kbase,
                   int row, half8* breg) {
  const int kf = ((threadIdx.x >> 4) & 3) * 8;
  const float* wr = w + (long)row * Kfull + kbase + kf;
  const float* mr = mask ? (mask + (long)row * Kfull + kbase + kf) : nullptr;
#pragma unroll
  for (int c = 0; c < NC; ++c) {
    f32x4 v0 = *(const f32x4*)(wr + c * 32);
    f32x4 v1 = *(const f32x4*)(wr + c * 32 + 4);
    if (mr) {
      v0 *= *(const f32x4*)(mr + c * 32);
      v1 *= *(const f32x4*)(mr + c * 32 + 4);
    }
    half8 h;
#pragma unroll
    for (int j = 0; j < 4; ++j) { h[j] = (_Float16)v0[j]; h[j + 4] = (_Float16)v1[j]; }
    breg[c] = h;
  }
}

// 32-row m-iter GEMM: A (hi+lo fp16 planes) x register-resident B.
// Chunks c < SC read (pah,pal,stride sa); c >= SC read (pbh,pbl,sb).
template <int NC, int SC>
DEVINL void gemm32(const _Float16* pah, const _Float16* pal, int sa,
                   const _Float16* pbh, const _Float16* pbl, int sb,
                   int mbase, const half8* breg, f32x4* acc) {
  const int lr = threadIdx.x & 15;
  const int kf = ((threadIdx.x >> 4) & 3) * 8;
#pragma unroll
  for (int c = 0; c < NC; ++c) {
    const int kk = c * 32 + kf;
    half8 ah[2], al[2];
#pragma unroll
    for (int s = 0; s < 2; ++s) {
      const int m = mbase + s * 16 + lr;
      if (c < SC) {
        ah[s] = *(const half8*)(pah + (long)m * sa + kk);
        al[s] = *(const half8*)(pal + (long)m * sa + kk);
      } else {
        ah[s] = *(const half8*)(pbh + (long)m * sb + (kk - SC * 32));
        al[s] = *(const half8*)(pbl + (long)m * sb + (kk - SC * 32));
      }
    }
#pragma unroll
    for (int s = 0; s < 2; ++s) {
      acc[s] = MF(ah[s], breg[c], acc[s]);
      acc[s] = MF(al[s], breg[c], acc[s]);
    }
  }
}

// Epilogue: stage 4 gates' accs to LDS, combine into h, write h hi/lo planes
// (+ final output for L2 at t=63).
template <int HH, bool ISL0, bool ISL2>
DEVINL void epi32(float* lds, const f32x4* acc, int mbase, int n0,
                  float bf1, float bf2, float bta, float btb,
                  const float* xacc, _Float16* oh, _Float16* ol,
                  float* out, int t) {
  const int g = threadIdx.x >> 6;
  const int lr = threadIdx.x & 15;
  const int lq = (threadIdx.x >> 4) & 3;
  __syncthreads();   // protect LDS from previous m-iter's readers
#pragma unroll
  for (int s = 0; s < 2; ++s)
#pragma unroll
    for (int r = 0; r < 4; ++r)
      lds[g * 512 + (s * 16 + lq * 4 + r) * 16 + lr] = acc[s][r];
  __syncthreads();
#pragma unroll
  for (int e0 = 0; e0 < 2; ++e0) {
    const int e = e0 * 256 + threadIdx.x;
    const int mloc = e >> 4, n = e & 15;
    float a0 = lds[e], a1 = lds[512 + e], a2 = lds[1024 + e], a3 = lds[1536 + e];
    const int row = mbase + mloc;
    if constexpr (ISL0) {
      const float* xb = xacc + (long)row * 2048 + n0 + n;
      a0 += xb[0]; a1 += xb[512]; a2 += xb[1024]; a3 += xb[1536];
    }
    float vf1 = a0 + bf1, vf2 = a1 + bf2;
    float vt = (a2 + bta) + (a3 + btb);            // ts = 1.0
    float ff1 = tanhf(vf1), ff2 = tanhf(vf2);
    float ti = 1.0f / (1.0f + __expf(-vt));
    float hv = ff1 + ti * (ff2 - ff1);
    _Float16 hh = (_Float16)hv;
    oh[(long)row * HH + n0 + n] = hh;
    ol[(long)row * HH + n0 + n] = (_Float16)(hv - (float)hh);
    if constexpr (ISL2) {
      if (t == 63) out[row * 64 + n0 + n] = hv;
    }
  }
}

__global__ __launch_bounds__(256, 2) void cfc_persist(Params p) {
  __shared__ float lds[2048];
  const int bid = blockIdx.x;
  const int g = threadIdx.x >> 6;        // wave index = gate
  const int lr = threadIdx.x & 15;
  const int lq = (threadIdx.x >> 4) & 3;
  const f32x4 zz = {0.f, 0.f, 0.f, 0.f};

  // ---- startup: zero h ping-pong planes (ws poisoned 0xAA each call) ----
  for (int i = bid * 256 + threadIdx.x; i < p.hzN; i += 256 * 256) p.hz[i] = 0u;

  if (bid < 128) {
    // ============ XG: split x(t+2), then x-part GEMM for t = s+1 ============
    const int nt = bid & 31, mq = bid >> 5;
    const int n0 = nt * 16, m0 = mq * 128;
    const float* w = (g == 0) ? p.w0f1 : (g == 1) ? p.w0f2 : (g == 2) ? p.w0ta : p.w0tb;
    half8 breg[24];
    load_b<24>(w, (g < 2) ? p.m0 : nullptr, 1280, 0, n0 + lr, breg);
    const int col = g * 512 + n0 + lr;
    const int xtid = bid * 256 + threadIdx.x;          // [0, 32768)
    for (int s = -2; s < 66; ++s) {
      gridbar(p.bar, (unsigned)(s + 3));
      // -- split x(t2 = s+2) fp32 -> fp16 hi/lo planes (buf t2&1) --
      const int t2 = s + 2;
      if (t2 >= 0 && t2 < 64) {
        _Float16* xh = (t2 & 1) ? p.xh1 : p.xh0;
        _Float16* xl = (t2 & 1) ? p.xl1 : p.xl0;
        for (int i = xtid; i < 49152; i += 32768) {    // 512 rows * 96 8-groups
          const int m = i / 96;
          const int k = (i - m * 96) * 8;
          const float* src = (k < 256) ? (p.base + ((long)m * 64 + t2) * 256 + k)
                                       : (p.visual + ((long)m * 64 + t2) * 512 + (k - 256));
          const f32x4* q = (const f32x4*)src;
          f32x4 v0 = q[0], v1 = q[1];
          half8 hh, ll;
#pragma unroll
          for (int j = 0; j < 4; ++j) {
            _Float16 a = (_Float16)v0[j]; hh[j] = a;     ll[j]     = (_Float16)(v0[j] - (float)a);
            _Float16 c = (_Float16)v1[j]; hh[j + 4] = c; ll[j + 4] = (_Float16)(v1[j] - (float)c);
          }
          *(half8*)(xh + (long)m * 768 + k) = hh;
          *(half8*)(xl + (long)m * 768 + k) = ll;
        }
      }
      // -- x-part GEMM for t = s+1 --
      const int t = s + 1;
      if (t < 0 || t >= 64) continue;
      const _Float16* xh = (t & 1) ? p.xh1 : p.xh0;
      const _Float16* xl = (t & 1) ? p.xl1 : p.xl0;
      float* xacc = (t & 1) ? p.xacc1 : p.xacc0;
      for (int mi = 0; mi < 4; ++mi) {
        f32x4 acc[2] = {zz, zz};
        gemm32<24, 24>(xh, xl, 768, nullptr, nullptr, 0, m0 + mi * 32, breg, acc);
#pragma unroll
        for (int ss = 0; ss < 2; ++ss)
#pragma unroll
          for (int r = 0; r < 4; ++r)
            xacc[(long)(m0 + mi * 32 + ss * 16 + lq * 4 + r) * 2048 + col] = acc[ss][r];
      }
    }
  } else if (bid < 192) {
    // ================= R0: L0 recurrent part for t = s =================
    const int b = bid - 128;
    const int nt = b & 31, mh = b >> 5;
    const int n0 = nt * 16, m0 = mh * 256;
    const float* w = (g == 0) ? p.w0f1 : (g == 1) ? p.w0f2 : (g == 2) ? p.w0ta : p.w0tb;
    half8 breg[16];
    load_b<16>(w, nullptr, 1280, 768, n0 + lr, breg);   // rec block of mask is all-ones
    const int ne = n0 + (threadIdx.x & 15);
    const float bf1 = p.b0f1[ne], bf2 = p.b0f2[ne], bta = p.b0ta[ne], btb = p.b0tb[ne];
    for (int s = -2; s < 66; ++s) {
      gridbar(p.bar, (unsigned)(s + 3));
      const int t = s;
      if (t < 0 || t >= 64) continue;
      const _Float16* pah = (t & 1) ? p.h0h0 : p.h0h1;   // h0(t-1)
      const _Float16* pal = (t & 1) ? p.h0l0 : p.h0l1;
      _Float16* oh = (t & 1) ? p.h0h1 : p.h0h0;          // h0(t)
      _Float16* ol = (t & 1) ? p.h0l1 : p.h0l0;
      const float* xacc = (t & 1) ? p.xacc1 : p.xacc0;
      for (int mi = 0; mi < 8; ++mi) {
        f32x4 acc[2] = {zz, zz};
        gemm32<16, 16>(pah, pal, 512, nullptr, nullptr, 0, m0 + mi * 32, breg, acc);
        epi32<512, true, false>(lds, acc, m0 + mi * 32, n0, bf1, bf2, bta, btb,
                                xacc, oh, ol, nullptr, t);
      }
    }
  } else {
    // ========== R1: L1 for t = s-1, then R2: L2 for t = s-2 ==========
    const int b = bid - 192;
    const int nt = b & 15, mq = b >> 4;
    const int n0 = nt * 16, m0 = mq * 128;
    const float* w1 = (g == 0) ? p.w1f1 : (g == 1) ? p.w1f2 : (g == 2) ? p.w1ta : p.w1tb;
    half8 breg1[24];
    load_b<24>(w1, (g < 2) ? p.m1 : nullptr, 768, 0, n0 + lr, breg1);
    const float* w2 = (g == 0) ? p.w2f1 : (g == 1) ? p.w2f2 : (g == 2) ? p.w2ta : p.w2tb;
    const int n2 = (b & 3) * 16, m2 = (b >> 2) * 32;     // L2 sub-tile: 32 rows x 16 cols
    half8 breg2[10];
    load_b<10>(w2, (g < 2) ? p.m2 : nullptr, 320, 0, n2 + lr, breg2);
    const int ne1 = n0 + (threadIdx.x & 15);
    const float c1f1 = p.b1f1[ne1], c1f2 = p.b1f2[ne1], c1ta = p.b1ta[ne1], c1tb = p.b1tb[ne1];
    const int ne2 = n2 + (threadIdx.x & 15);
    const float c2f1 = p.b2f1[ne2], c2f2 = p.b2f2[ne2], c2ta = p.b2ta[ne2], c2tb = p.b2tb[ne2];
    for (int s = -2; s < 66; ++s) {
      gridbar(p.bar, (unsigned)(s + 3));
      {  // ---- L1, t = s-1 ----
        const int t = s - 1;
        if (t >= 0 && t < 64) {
          const _Float16* pah = (t & 1) ? p.h0h1 : p.h0h0;   // h0(t)
          const _Float16* pal = (t & 1) ? p.h0l1 : p.h0l0;
          const _Float16* qah = (t & 1) ? p.h1h0 : p.h1h1;   // h1(t-1)
          const _Float16* qal = (t & 1) ? p.h1l0 : p.h1l1;
          _Float16* oh = (t & 1) ? p.h1h1 : p.h1h0;          // h1(t)
          _Float16* ol = (t & 1) ? p.h1l1 : p.h1l0;
          for (int mi = 0; mi < 4; ++mi) {
            f32x4 acc[2] = {zz, zz};
            gemm32<24, 16>(pah, pal, 512, qah, qal, 256, m0 + mi * 32, breg1, acc);
            epi32<256, false, false>(lds, acc, m0 + mi * 32, n0, c1f1, c1f2, c1ta, c1tb,
                                     nullptr, oh, ol, nullptr, t);
          }
        }
      }
      {  // ---- L2, t = s-2 ----
        const int t = s - 2;
        if (t >= 0 && t < 64) {
          const _Float16* pah = (t & 1) ? p.h1h1 : p.h1h0;   // h1(t)
          const _Float16* pal = (t & 1) ? p.h1l1 : p.h1l0;
          const _Float16* qah = (t & 1) ? p.h2h0 : p.h2h1;   // h2(t-1)
          const _Float16* qal = (t & 1) ? p.h2l0 : p.h2l1;
          _Float16* oh = (t & 1) ? p.h2h1 : p.h2h0;          // h2(t)
          _Float16* ol = (t & 1) ? p.h2l1 : p.h2l0;
          f32x4 acc[2] = {zz, zz};
          gemm32<10, 8>(pah, pal, 256, qah, qal, 64, m2, breg2, acc);
          epi32<64, false, true>(lds, acc, m2, n2, c2f1, c2f2, c2ta, c2tb,
                                 nullptr, oh, ol, p.out, t);
        }
      }
    }
  }
}

__global__ void zero_bar(unsigned* __restrict__ b, int n) {
  int i = blockIdx.x * 256 + threadIdx.x;
  if (i < n) b[i] = 0u;
}

extern "C" void kernel_launch(void* const* d_in, const int* in_sizes, int n_in,
                              void* d_out, int out_size, void* d_ws, size_t ws_size,
                              hipStream_t stream) {
  // ---- workspace layout (units: _Float16) ----
  _Float16* W = (_Float16*)d_ws;
  _Float16* xh0 = W;                    // 512*768 = 393,216 each
  _Float16* xl0 = xh0 + 393216;
  _Float16* xh1 = xl0 + 393216;
  _Float16* xl1 = xh1 + 393216;
  _Float16* hb  = xl1 + 393216;         // h region (zeroed in-kernel)
  _Float16* h0h0 = hb;            _Float16* h0h1 = h0h0 + 262144;
  _Float16* h0l0 = h0h1 + 262144; _Float16* h0l1 = h0l0 + 262144;
  _Float16* h1h0 = h0l1 + 262144; _Float16* h1h1 = h1h0 + 131072;
  _Float16* h1l0 = h1h1 + 131072; _Float16* h1l1 = h1l0 + 131072;
  _Float16* h2h0 = h1l1 + 131072; _Float16* h2h1 = h2h0 + 32768;
  _Float16* h2l0 = h2h1 + 32768;  _Float16* h2l1 = h2l0 + 32768;
  float* xacc0 = (float*)(h2l1 + 32768);   // 512*2048 fp32 each
  float* xacc1 = xacc0 + 1048576;
  unsigned* bar = (unsigned*)(xacc1 + 1048576);  // 4352 uints; total ws ≈ 14.9 MB

  auto in = [&](int i) { return (const float*)d_in[i]; };

  Params p;
  p.base = in(0); p.visual = in(1);
  p.w0f1 = in(2);  p.b0f1 = in(3);  p.w0f2 = in(4);  p.b0f2 = in(5);
  p.w0ta = in(6);  p.b0ta = in(7);  p.w0tb = in(8);  p.b0tb = in(9);  p.m0 = in(10);
  p.w1f1 = in(11); p.b1f1 = in(12); p.w1f2 = in(13); p.b1f2 = in(14);
  p.w1ta = in(15); p.b1ta = in(16); p.w1tb = in(17); p.b1tb = in(18); p.m1 = in(19);
  p.w2f1 = in(20); p.b2f1 = in(21); p.w2f2 = in(22); p.b2f2 = in(23);
  p.w2ta = in(24); p.b2ta = in(25); p.w2tb = in(26); p.b2tb = in(27); p.m2 = in(28);
  p.xh0 = xh0; p.xl0 = xl0; p.xh1 = xh1; p.xl1 = xl1;
  p.xacc0 = xacc0; p.xacc1 = xacc1;
  p.h0h0 = h0h0; p.h0h1 = h0h1; p.h0l0 = h0l0; p.h0l1 = h0l1;
  p.h1h0 = h1h0; p.h1h1 = h1h1; p.h1l0 = h1l0; p.h1l1 = h1l1;
  p.h2h0 = h2h0; p.h2h1 = h2h1; p.h2l0 = h2l0; p.h2l1 = h2l1;
  p.hz = (unsigned*)hb; p.hzN = 1703936 / 2;
  p.bar = bar;
  p.out = (float*)d_out;

  zero_bar<<<17, 256, 0, stream>>>(bar, 4352);
  cfc_persist<<<256, 256, 0, stream>>>(p);
}

// Round 6
// 4816.555 us; speedup vs baseline: 1.5623x; 1.5623x over previous
//
#include <hip/hip_runtime.h>
#include <cmath>

// CfC encoder, persistent kernel. R6: relaxed-poll barrier (ONE acquire fence
// per block per step, polls don't invalidate caches) + 512 blocks for 2x
// latency hiding. Plain launch; 128 VGPR/256thr => >=2 blocks/CU capacity,
// all 512 blocks resident at dispatch => spin barrier cannot deadlock.
// Roles by blockIdx: [0,256)   XG: split x(t+2) -> fp16 planes + x-part GEMM (t+1)
//                    [256,384) R0: L0 recurrent GEMM + epilogue (t); b<64 also L2 (t-2)
//                    [384,512) R1: L1 (t-1)
// Block = 4 waves = 4 gates (ff1,ff2,ta,tb); epilogue combines gates via LDS.
//
// Barrier (uint, 64B-strided): slot[i]=bar[i*16] i<512; flag[g]=bar[8192+g*16] g<16.
// Arrive: release-fence once, relaxed store slot. Block 0 wave 0 sweeps slots
// (relaxed), relaxed-stores 16 flags. Others poll own flag line (relaxed).
// After release observed: ONE acquire fence (agent) -> caches invalidated once.

typedef __attribute__((ext_vector_type(8))) _Float16 half8;
typedef __attribute__((ext_vector_type(4))) float f32x4;

#define DEVINL __device__ __forceinline__

DEVINL f32x4 MF(half8 a, half8 b, f32x4 c) {
  return __builtin_amdgcn_mfma_f32_16x16x32_f16(a, b, c, 0, 0, 0);
}

DEVINL void gridbar(unsigned* bar, unsigned k) {
  __syncthreads();                       // block done with prior step's work
  if (threadIdx.x == 0) {
    __builtin_amdgcn_fence(__ATOMIC_RELEASE, "agent");   // write back my data once
    __hip_atomic_store(bar + blockIdx.x * 16, k, __ATOMIC_RELAXED,
                       __HIP_MEMORY_SCOPE_AGENT);
  }
  if (blockIdx.x == 0) {
    if (threadIdx.x < 64) {
      const int i0 = threadIdx.x * 8;    // this lane owns slots i0..i0+7
      for (;;) {
        bool ok = true;
#pragma unroll
        for (int j = 0; j < 8; ++j) {
          unsigned v = __hip_atomic_load(bar + (i0 + j) * 16, __ATOMIC_RELAXED,
                                         __HIP_MEMORY_SCOPE_AGENT);
          ok &= (v >= k);
        }
        if (__ballot(ok) == ~0ull) break;
        __builtin_amdgcn_s_sleep(8);
      }
      if (threadIdx.x < 16)
        __hip_atomic_store(bar + 8192 + threadIdx.x * 16, k, __ATOMIC_RELAXED,
                           __HIP_MEMORY_SCOPE_AGENT);
    }
  } else if (threadIdx.x == 0) {
    const unsigned g = blockIdx.x & 15;  // 32 pollers per flag line
    while (__hip_atomic_load(bar + 8192 + g * 16, __ATOMIC_RELAXED,
                             __HIP_MEMORY_SCOPE_AGENT) < k)
      __builtin_amdgcn_s_sleep(8);
  }
  if (threadIdx.x == 0)
    __builtin_amdgcn_fence(__ATOMIC_ACQUIRE, "agent");   // invalidate stale caches ONCE
  __syncthreads();
}

struct Params {
  const float *base, *visual;
  const float *w0f1, *w0f2, *w0ta, *w0tb, *m0;
  const float *b0f1, *b0f2, *b0ta, *b0tb;
  const float *w1f1, *w1f2, *w1ta, *w1tb, *m1;
  const float *b1f1, *b1f2, *b1ta, *b1tb;
  const float *w2f1, *w2f2, *w2ta, *w2tb, *m2;
  const float *b2f1, *b2f2, *b2ta, *b2tb;
  _Float16 *xh0, *xl0, *xh1, *xl1;        // x split planes, 512*768, buf = t&1
  float *xacc0, *xacc1;                   // x pre-GEMM out, 512*2048 fp32, buf = t&1
  _Float16 *h0h0, *h0h1, *h0l0, *h0l1;    // h(t) lives in buf t&1
  _Float16 *h1h0, *h1h1, *h1l0, *h1l1;
  _Float16 *h2h0, *h2h1, *h2l0, *h2l1;
  unsigned *hz; int hzN;                  // h region to zero at startup
  unsigned *bar;                          // barrier scoreboard (pre-zeroed)
  float *out;
};

// Load one wave's B slice: rows = 16 neurons (lane&15), cols = K-range,
// from fp32 weights (+optional mask), converted to fp16, into VGPRs.
template <int NC>
DEVINL void load_b(const float* w, const float* mask, int Kfull, int kbase,
                   int row, half8* breg) {
  const int kf = ((threadIdx.x >> 4) & 3) * 8;
  const float* wr = w + (long)row * Kfull + kbase + kf;
  const float* mr = mask ? (mask + (long)row * Kfull + kbase + kf) : nullptr;
#pragma unroll
  for (int c = 0; c < NC; ++c) {
    f32x4 v0 = *(const f32x4*)(wr + c * 32);
    f32x4 v1 = *(const f32x4*)(wr + c * 32 + 4);
    if (mr) {
      v0 *= *(const f32x4*)(mr + c * 32);
      v1 *= *(const f32x4*)(mr + c * 32 + 4);
    }
    half8 h;
#pragma unroll
    for (int j = 0; j < 4; ++j) { h[j] = (_Float16)v0[j]; h[j + 4] = (_Float16)v1[j]; }
    breg[c] = h;
  }
}

// 32-row m-iter GEMM: A (hi+lo fp16 planes) x register-resident B.
// Chunks c < SC read (pah,pal,stride sa); c >= SC read (pbh,pbl,sb).
template <int NC, int SC>
DEVINL void gemm32(const _Float16* pah, const _Float16* pal, int sa,
                   const _Float16* pbh, const _Float16* pbl, int sb,
                   int mbase, const half8* breg, f32x4* acc) {
  const int lr = threadIdx.x & 15;
  const int kf = ((threadIdx.x >> 4) & 3) * 8;
#pragma unroll
  for (int c = 0; c < NC; ++c) {
    const int kk = c * 32 + kf;
    half8 ah[2], al[2];
#pragma unroll
    for (int s = 0; s < 2; ++s) {
      const int m = mbase + s * 16 + lr;
      if (c < SC) {
        ah[s] = *(const half8*)(pah + (long)m * sa + kk);
        al[s] = *(const half8*)(pal + (long)m * sa + kk);
      } else {
        ah[s] = *(const half8*)(pbh + (long)m * sb + (kk - SC * 32));
        al[s] = *(const half8*)(pbl + (long)m * sb + (kk - SC * 32));
      }
    }
#pragma unroll
    for (int s = 0; s < 2; ++s) {
      acc[s] = MF(ah[s], breg[c], acc[s]);
      acc[s] = MF(al[s], breg[c], acc[s]);
    }
  }
}

// Epilogue: stage 4 gates' accs to LDS, combine into h, write h hi/lo planes
// (+ final output for L2 at t=63).
template <int HH, bool ISL0, bool ISL2>
DEVINL void epi32(float* lds, const f32x4* acc, int mbase, int n0,
                  float bf1, float bf2, float bta, float btb,
                  const float* xacc, _Float16* oh, _Float16* ol,
                  float* out, int t) {
  const int g = threadIdx.x >> 6;
  const int lr = threadIdx.x & 15;
  const int lq = (threadIdx.x >> 4) & 3;
  __syncthreads();   // protect LDS from previous m-iter's readers
#pragma unroll
  for (int s = 0; s < 2; ++s)
#pragma unroll
    for (int r = 0; r < 4; ++r)
      lds[g * 512 + (s * 16 + lq * 4 + r) * 16 + lr] = acc[s][r];
  __syncthreads();
#pragma unroll
  for (int e0 = 0; e0 < 2; ++e0) {
    const int e = e0 * 256 + threadIdx.x;
    const int mloc = e >> 4, n = e & 15;
    float a0 = lds[e], a1 = lds[512 + e], a2 = lds[1024 + e], a3 = lds[1536 + e];
    const int row = mbase + mloc;
    if constexpr (ISL0) {
      const float* xb = xacc + (long)row * 2048 + n0 + n;
      a0 += xb[0]; a1 += xb[512]; a2 += xb[1024]; a3 += xb[1536];
    }
    float vf1 = a0 + bf1, vf2 = a1 + bf2;
    float vt = (a2 + bta) + (a3 + btb);            // ts = 1.0
    float ff1 = tanhf(vf1), ff2 = tanhf(vf2);
    float ti = 1.0f / (1.0f + __expf(-vt));
    float hv = ff1 + ti * (ff2 - ff1);
    _Float16 hh = (_Float16)hv;
    oh[(long)row * HH + n0 + n] = hh;
    ol[(long)row * HH + n0 + n] = (_Float16)(hv - (float)hh);
    if constexpr (ISL2) {
      if (t == 63) out[row * 64 + n0 + n] = hv;
    }
  }
}

__global__ __launch_bounds__(256, 2) void cfc_persist(Params p) {
  __shared__ float lds[2048];
  const int bid = blockIdx.x;
  const int g = threadIdx.x >> 6;        // wave index = gate
  const int lr = threadIdx.x & 15;
  const int lq = (threadIdx.x >> 4) & 3;
  const f32x4 zz = {0.f, 0.f, 0.f, 0.f};

  // ---- startup: zero h ping-pong planes (ws poisoned 0xAA each call) ----
  for (int i = bid * 256 + threadIdx.x; i < p.hzN; i += 512 * 256) p.hz[i] = 0u;

  if (bid < 256) {
    // ============ XG: split x(t+2), then x-part GEMM for t = s+1 ============
    const int nt = bid & 31, mq = bid >> 5;        // 8 m-tiles of 64 rows
    const int n0 = nt * 16, m0 = mq * 64;
    const float* w = (g == 0) ? p.w0f1 : (g == 1) ? p.w0f2 : (g == 2) ? p.w0ta : p.w0tb;
    half8 breg[24];
    load_b<24>(w, (g < 2) ? p.m0 : nullptr, 1280, 0, n0 + lr, breg);
    const int col = g * 512 + n0 + lr;
    const int xtid = bid * 256 + threadIdx.x;      // [0, 65536)
    for (int s = -2; s < 66; ++s) {
      gridbar(p.bar, (unsigned)(s + 3));
      // -- split x(t2 = s+2) fp32 -> fp16 hi/lo planes (buf t2&1) --
      const int t2 = s + 2;
      if (t2 >= 0 && t2 < 64 && xtid < 49152) {    // 512 rows * 96 8-groups
        _Float16* xh = (t2 & 1) ? p.xh1 : p.xh0;
        _Float16* xl = (t2 & 1) ? p.xl1 : p.xl0;
        const int m = xtid / 96;
        const int k = (xtid - m * 96) * 8;
        const float* src = (k < 256) ? (p.base + ((long)m * 64 + t2) * 256 + k)
                                     : (p.visual + ((long)m * 64 + t2) * 512 + (k - 256));
        const f32x4* q = (const f32x4*)src;
        f32x4 v0 = q[0], v1 = q[1];
        half8 hh, ll;
#pragma unroll
        for (int j = 0; j < 4; ++j) {
          _Float16 a = (_Float16)v0[j]; hh[j] = a;     ll[j]     = (_Float16)(v0[j] - (float)a);
          _Float16 c = (_Float16)v1[j]; hh[j + 4] = c; ll[j + 4] = (_Float16)(v1[j] - (float)c);
        }
        *(half8*)(xh + (long)m * 768 + k) = hh;
        *(half8*)(xl + (long)m * 768 + k) = ll;
      }
      // -- x-part GEMM for t = s+1 --
      const int t = s + 1;
      if (t < 0 || t >= 64) continue;
      const _Float16* xh = (t & 1) ? p.xh1 : p.xh0;
      const _Float16* xl = (t & 1) ? p.xl1 : p.xl0;
      float* xacc = (t & 1) ? p.xacc1 : p.xacc0;
      for (int mi = 0; mi < 2; ++mi) {
        f32x4 acc[2] = {zz, zz};
        gemm32<24, 24>(xh, xl, 768, nullptr, nullptr, 0, m0 + mi * 32, breg, acc);
#pragma unroll
        for (int ss = 0; ss < 2; ++ss)
#pragma unroll
          for (int r = 0; r < 4; ++r)
            xacc[(long)(m0 + mi * 32 + ss * 16 + lq * 4 + r) * 2048 + col] = acc[ss][r];
      }
    }
  } else if (bid < 384) {
    // ========= R0: L0 recurrent for t = s; blocks b<64 also L2 (t-2) =========
    const int b = bid - 256;
    const int nt = b & 31, mh = b >> 5;            // 4 m-tiles of 128 rows
    const int n0 = nt * 16, m0 = mh * 128;
    const float* w = (g == 0) ? p.w0f1 : (g == 1) ? p.w0f2 : (g == 2) ? p.w0ta : p.w0tb;
    half8 breg[16];
    load_b<16>(w, nullptr, 1280, 768, n0 + lr, breg);   // rec block of mask is all-ones
    const int ne = n0 + (threadIdx.x & 15);
    const float bf1 = p.b0f1[ne], bf2 = p.b0f2[ne], bta = p.b0ta[ne], btb = p.b0tb[ne];
    // L2 sub-role for b < 64: 32 rows x 16 cols
    const bool doL2 = (b < 64);
    const int n2 = (b & 3) * 16, m2 = (b >> 2) * 32;
    half8 breg2[10];
    if (doL2) {
      const float* w2 = (g == 0) ? p.w2f1 : (g == 1) ? p.w2f2 : (g == 2) ? p.w2ta : p.w2tb;
      load_b<10>(w2, (g < 2) ? p.m2 : nullptr, 320, 0, n2 + lr, breg2);
    }
    const int ne2 = n2 + (threadIdx.x & 15);
    const float c2f1 = p.b2f1[ne2], c2f2 = p.b2f2[ne2], c2ta = p.b2ta[ne2], c2tb = p.b2tb[ne2];
    for (int s = -2; s < 66; ++s) {
      gridbar(p.bar, (unsigned)(s + 3));
      {  // ---- L0 rec, t = s ----
        const int t = s;
        if (t >= 0 && t < 64) {
          const _Float16* pah = (t & 1) ? p.h0h0 : p.h0h1;   // h0(t-1)
          const _Float16* pal = (t & 1) ? p.h0l0 : p.h0l1;
          _Float16* oh = (t & 1) ? p.h0h1 : p.h0h0;          // h0(t)
          _Float16* ol = (t & 1) ? p.h0l1 : p.h0l0;
          const float* xacc = (t & 1) ? p.xacc1 : p.xacc0;
          for (int mi = 0; mi < 4; ++mi) {
            f32x4 acc[2] = {zz, zz};
            gemm32<16, 16>(pah, pal, 512, nullptr, nullptr, 0, m0 + mi * 32, breg, acc);
            epi32<512, true, false>(lds, acc, m0 + mi * 32, n0, bf1, bf2, bta, btb,
                                    xacc, oh, ol, nullptr, t);
          }
        }
      }
      if (doL2) {  // ---- L2, t = s-2 ----
        const int t = s - 2;
        if (t >= 0 && t < 64) {
          const _Float16* pah = (t & 1) ? p.h1h1 : p.h1h0;   // h1(t)
          const _Float16* pal = (t & 1) ? p.h1l1 : p.h1l0;
          const _Float16* qah = (t & 1) ? p.h2h0 : p.h2h1;   // h2(t-1)
          const _Float16* qal = (t & 1) ? p.h2l0 : p.h2l1;
          _Float16* oh = (t & 1) ? p.h2h1 : p.h2h0;          // h2(t)
          _Float16* ol = (t & 1) ? p.h2l1 : p.h2l0;
          f32x4 acc[2] = {zz, zz};
          gemm32<10, 8>(pah, pal, 256, qah, qal, 64, m2, breg2, acc);
          epi32<64, false, true>(lds, acc, m2, n2, c2f1, c2f2, c2ta, c2tb,
                                 nullptr, oh, ol, p.out, t);
        }
      }
    }
  } else {
    // ================= R1: L1 for t = s-1 =================
    const int b = bid - 384;
    const int nt = b & 15, mq = b >> 4;            // 8 m-tiles of 64 rows
    const int n0 = nt * 16, m0 = mq * 64;
    const float* w1 = (g == 0) ? p.w1f1 : (g == 1) ? p.w1f2 : (g == 2) ? p.w1ta : p.w1tb;
    half8 breg1[24];
    load_b<24>(w1, (g < 2) ? p.m1 : nullptr, 768, 0, n0 + lr, breg1);
    const int ne1 = n0 + (threadIdx.x & 15);
    const float c1f1 = p.b1f1[ne1], c1f2 = p.b1f2[ne1], c1ta = p.b1ta[ne1], c1tb = p.b1tb[ne1];
    for (int s = -2; s < 66; ++s) {
      gridbar(p.bar, (unsigned)(s + 3));
      const int t = s - 1;
      if (t < 0 || t >= 64) continue;
      const _Float16* pah = (t & 1) ? p.h0h1 : p.h0h0;   // h0(t)
      const _Float16* pal = (t & 1) ? p.h0l1 : p.h0l0;
      const _Float16* qah = (t & 1) ? p.h1h0 : p.h1h1;   // h1(t-1)
      const _Float16* qal = (t & 1) ? p.h1l0 : p.h1l1;
      _Float16* oh = (t & 1) ? p.h1h1 : p.h1h0;          // h1(t)
      _Float16* ol = (t & 1) ? p.h1l1 : p.h1l0;
      for (int mi = 0; mi < 2; ++mi) {
        f32x4 acc[2] = {zz, zz};
        gemm32<24, 16>(pah, pal, 512, qah, qal, 256, m0 + mi * 32, breg1, acc);
        epi32<256, false, false>(lds, acc, m0 + mi * 32, n0, c1f1, c1f2, c1ta, c1tb,
                                 nullptr, oh, ol, nullptr, t);
      }
    }
  }
}

__global__ void zero_bar(unsigned* __restrict__ b, int n) {
  int i = blockIdx.x * 256 + threadIdx.x;
  if (i < n) b[i] = 0u;
}

extern "C" void kernel_launch(void* const* d_in, const int* in_sizes, int n_in,
                              void* d_out, int out_size, void* d_ws, size_t ws_size,
                              hipStream_t stream) {
  // ---- workspace layout (units: _Float16) ----
  _Float16* W = (_Float16*)d_ws;
  _Float16* xh0 = W;                    // 512*768 = 393,216 each
  _Float16* xl0 = xh0 + 393216;
  _Float16* xh1 = xl0 + 393216;
  _Float16* xl1 = xh1 + 393216;
  _Float16* hb  = xl1 + 393216;         // h region (zeroed in-kernel)
  _Float16* h0h0 = hb;            _Float16* h0h1 = h0h0 + 262144;
  _Float16* h0l0 = h0h1 + 262144; _Float16* h0l1 = h0l0 + 262144;
  _Float16* h1h0 = h0l1 + 262144; _Float16* h1h1 = h1h0 + 131072;
  _Float16* h1l0 = h1h1 + 131072; _Float16* h1l1 = h1l0 + 131072;
  _Float16* h2h0 = h1l1 + 131072; _Float16* h2h1 = h2h0 + 32768;
  _Float16* h2l0 = h2h1 + 32768;  _Float16* h2l1 = h2l0 + 32768;
  float* xacc0 = (float*)(h2l1 + 32768);   // 512*2048 fp32 each
  float* xacc1 = xacc0 + 1048576;
  unsigned* bar = (unsigned*)(xacc1 + 1048576);  // 8448 uints; total ws ≈ 14.9 MB

  auto in = [&](int i) { return (const float*)d_in[i]; };

  Params p;
  p.base = in(0); p.visual = in(1);
  p.w0f1 = in(2);  p.b0f1 = in(3);  p.w0f2 = in(4);  p.b0f2 = in(5);
  p.w0ta = in(6);  p.b0ta = in(7);  p.w0tb = in(8);  p.b0tb = in(9);  p.m0 = in(10);
  p.w1f1 = in(11); p.b1f1 = in(12); p.w1f2 = in(13); p.b1f2 = in(14);
  p.w1ta = in(15); p.b1ta = in(16); p.w1tb = in(17); p.b1tb = in(18); p.m1 = in(19);
  p.w2f1 = in(20); p.b2f1 = in(21); p.w2f2 = in(22); p.b2f2 = in(23);
  p.w2ta = in(24); p.b2ta = in(25); p.w2tb = in(26); p.b2tb = in(27); p.m2 = in(28);
  p.xh0 = xh0; p.xl0 = xl0; p.xh1 = xh1; p.xl1 = xl1;
  p.xacc0 = xacc0; p.xacc1 = xacc1;
  p.h0h0 = h0h0; p.h0h1 = h0h1; p.h0l0 = h0l0; p.h0l1 = h0l1;
  p.h1h0 = h1h0; p.h1h1 = h1h1; p.h1l0 = h1l0; p.h1l1 = h1l1;
  p.h2h0 = h2h0; p.h2h1 = h2h1; p.h2l0 = h2l0; p.h2l1 = h2l1;
  p.hz = (unsigned*)hb; p.hzN = 1703936 / 2;
  p.bar = bar;
  p.out = (float*)d_out;

  zero_bar<<<33, 256, 0, stream>>>(bar, 8448);
  cfc_persist<<<512, 256, 0, stream>>>(p);
}

// Round 7
// 3574.005 us; speedup vs baseline: 2.1055x; 1.3477x over previous
//
#include <hip/hip_runtime.h>
#include <cmath>

// CfC encoder, persistent kernel R7: weights in LDS (loaded once, read-only),
// VGPRs freed for deep A-load pipelining. Lane-local gate combine (wave owns
// all gates of an m-slice) -> no epilogue LDS, no K-loop syncthreads.
// 400 blocks x 256 thr, 64KB LDS, 2 blocks/CU capacity -> all resident.
// Pipeline stages at step s:
//   XP(s)      split x -> fp16 planes            [in XG blocks]
//   XG(s-1)    x-part of L0 (K=768)  -> xacc     blocks [0,128): gate-pair split
//   R0(s-2)    L0 recurrent (K=512)  -> h0       blocks [128,256)
//   R1x(s-3)   L1 h0-part (K=512)    -> r1acc    blocks [256,320): gate-pair
//   R1r(s-4)   L1 recurrent (K=256)  -> h1       blocks [320,384)
//   L2(s-5)    full L2 (K=320)       -> h2, out  blocks [384,400)

typedef __attribute__((ext_vector_type(8))) _Float16 half8;
typedef __attribute__((ext_vector_type(4))) float f32x4;

#define DEVINL __device__ __forceinline__

DEVINL f32x4 MF(half8 a, half8 b, f32x4 c) {
  return __builtin_amdgcn_mfma_f32_16x16x32_f16(a, b, c, 0, 0, 0);
}

// Relaxed-poll scoreboard barrier (R6 mechanism, 448 slots for 400 blocks;
// unused slots pre-set to 0xFFFFFFFF). One acquire fence per block per step.
DEVINL void gridbar(unsigned* bar, unsigned k) {
  __syncthreads();
  if (threadIdx.x == 0) {
    __builtin_amdgcn_fence(__ATOMIC_RELEASE, "agent");
    __hip_atomic_store(bar + blockIdx.x * 16, k, __ATOMIC_RELAXED,
                       __HIP_MEMORY_SCOPE_AGENT);
  }
  if (blockIdx.x == 0) {
    if (threadIdx.x < 64) {
      const int i0 = threadIdx.x * 7;
      for (;;) {
        bool ok = true;
#pragma unroll
        for (int j = 0; j < 7; ++j) {
          unsigned v = __hip_atomic_load(bar + (i0 + j) * 16, __ATOMIC_RELAXED,
                                         __HIP_MEMORY_SCOPE_AGENT);
          ok &= (v >= k);
        }
        if (__ballot(ok) == ~0ull) break;
        __builtin_amdgcn_s_sleep(8);
      }
      if (threadIdx.x < 16)
        __hip_atomic_store(bar + 7168 + threadIdx.x * 16, k, __ATOMIC_RELAXED,
                           __HIP_MEMORY_SCOPE_AGENT);
    }
  } else if (threadIdx.x == 0) {
    const unsigned gfl = blockIdx.x & 15;
    while (__hip_atomic_load(bar + 7168 + gfl * 16, __ATOMIC_RELAXED,
                             __HIP_MEMORY_SCOPE_AGENT) < k)
      __builtin_amdgcn_s_sleep(8);
  }
  if (threadIdx.x == 0)
    __builtin_amdgcn_fence(__ATOMIC_ACQUIRE, "agent");
  __syncthreads();
}

struct Params {
  const float *base, *visual;
  const float *w0f1, *w0f2, *w0ta, *w0tb, *m0;
  const float *b0f1, *b0f2, *b0ta, *b0tb;
  const float *w1f1, *w1f2, *w1ta, *w1tb, *m1;
  const float *b1f1, *b1f2, *b1ta, *b1tb;
  const float *w2f1, *w2f2, *w2ta, *w2tb, *m2;
  const float *b2f1, *b2f2, *b2ta, *b2tb;
  _Float16 *xh0, *xl0, *xh1, *xl1;        // x fp16 planes, 512*768, buf = t&1
  float *xacc0, *xacc1;                   // 512*2048 fp32, buf = t&1
  float *r1acc0, *r1acc1;                 // 512*1024 fp32, buf = t&1
  _Float16 *h0h0, *h0h1, *h0l0, *h0l1;    // h(t) lives in buf t&1
  _Float16 *h1h0, *h1h1, *h1l0, *h1l1;
  _Float16 *h2h0, *h2h1, *h2l0, *h2l1;
  unsigned *hz; int hzN;
  unsigned *bar;
  float *out;
};

// Startup: load block's B-tile (G gates x 16 n x NC*32 k) fp32 -> masked ->
// fp16 -> LDS. Layout: frag(gl,c,lane) at BL[((gl*NC+c)*64+lane)*8].
DEVINL void load_b_lds(_Float16* BL, const float* w0, const float* w1,
                       const float* w2, const float* w3, const float* mask,
                       int nmask, int G, int NC, int Kfull, int kofs, int n0) {
  const int wv = threadIdx.x >> 6, lane = threadIdx.x & 63;
  const int lr = lane & 15, lq = lane >> 4;
  for (int i = wv; i < G * NC; i += 4) {
    const int gl = i / NC, c = i - gl * NC;
    const float* wsrc = (gl == 0) ? w0 : (gl == 1) ? w1 : (gl == 2) ? w2 : w3;
    const long off = (long)(n0 + lr) * Kfull + kofs + c * 32 + lq * 8;
    f32x4 v0 = *(const f32x4*)(wsrc + off);
    f32x4 v1 = *(const f32x4*)(wsrc + off + 4);
    if (gl < nmask) {
      v0 *= *(const f32x4*)(mask + off);
      v1 *= *(const f32x4*)(mask + off + 4);
    }
    half8 h;
#pragma unroll
    for (int j = 0; j < 4; ++j) { h[j] = (_Float16)v0[j]; h[j + 4] = (_Float16)v1[j]; }
    *(half8*)(BL + ((long)i * 64 + lane) * 8) = h;
  }
}

// K-loop: B from LDS, A (hi+lo fp16) streamed from global with deep pipelining.
// Chunks c < SC read (pah,pal,sa); c >= SC read (qah,qal,sb).
template <int G, int NC, int MS, int SC>
DEVINL void kloop(const _Float16* BL,
                  const _Float16* pah, const _Float16* pal, long sa,
                  const _Float16* qah, const _Float16* qal, long sb,
                  int mw, f32x4 (&acc)[MS][G]) {
  const int lane = threadIdx.x & 63;
  const int lr = lane & 15, lq = lane >> 4;
#pragma unroll
  for (int c = 0; c < NC; ++c) {
    half8 bf[G];
#pragma unroll
    for (int gl = 0; gl < G; ++gl)
      bf[gl] = *(const half8*)(BL + ((gl * NC + c) * 64 + lane) * 8);
    const int kk = c * 32 + lq * 8;
#pragma unroll
    for (int s = 0; s < MS; ++s) {
      const long m = mw + s * 16 + lr;
      half8 ah, al;
      if (c < SC) {
        ah = *(const half8*)(pah + m * sa + kk);
        al = *(const half8*)(pal + m * sa + kk);
      } else {
        ah = *(const half8*)(qah + m * sb + (kk - SC * 32));
        al = *(const half8*)(qal + m * sb + (kk - SC * 32));
      }
#pragma unroll
      for (int gl = 0; gl < G; ++gl) {
        acc[s][gl] = MF(ah, bf[gl], acc[s][gl]);
        acc[s][gl] = MF(al, bf[gl], acc[s][gl]);
      }
    }
  }
}

// Pair-role store: acc -> fp32 partial buffer [row*OS + (gbase+gl)*HO + n0+lr]
template <int G, int MS>
DEVINL void store_pair(float* dst, long OS, int HO, int gbase, int mw, int n0,
                       f32x4 (&acc)[MS][G]) {
  const int lane = threadIdx.x & 63;
  const int lr = lane & 15, lq = lane >> 4;
#pragma unroll
  for (int s = 0; s < MS; ++s)
#pragma unroll
    for (int gl = 0; gl < G; ++gl)
#pragma unroll
      for (int r = 0; r < 4; ++r)
        dst[(long)(mw + s * 16 + lq * 4 + r) * OS + (gbase + gl) * HO + n0 + lr] =
            acc[s][gl][r];
}

// Full-gate epilogue, lane-local (wave owns all 4 gates). C/D: col=lane&15,
// row=(lane>>4)*4+reg (m89).
template <int MS, int HH, bool PRE, bool ISL2>
DEVINL void epi_full(const float* pre, long PS, int HO, int mw, int n0,
                     float bf1, float bf2, float bta, float btb,
                     _Float16* oh, _Float16* ol, float* out, int t,
                     f32x4 (&acc)[MS][4]) {
  const int lane = threadIdx.x & 63;
  const int lr = lane & 15, lq = lane >> 4;
#pragma unroll
  for (int s = 0; s < MS; ++s)
#pragma unroll
    for (int r = 0; r < 4; ++r) {
      const long row = mw + s * 16 + lq * 4 + r;
      float a0 = acc[s][0][r], a1 = acc[s][1][r], a2 = acc[s][2][r], a3 = acc[s][3][r];
      if constexpr (PRE) {
        const float* pb = pre + row * PS + n0 + lr;
        a0 += pb[0]; a1 += pb[HO]; a2 += pb[2 * HO]; a3 += pb[3 * HO];
      }
      float vf1 = a0 + bf1, vf2 = a1 + bf2;
      float vt = (a2 + bta) + (a3 + btb);            // ts = 1.0
      float ff1 = tanhf(vf1), ff2 = tanhf(vf2);
      float ti = 1.0f / (1.0f + __expf(-vt));
      float hv = ff1 + ti * (ff2 - ff1);
      _Float16 hh = (_Float16)hv;
      oh[row * HH + n0 + lr] = hh;
      ol[row * HH + n0 + lr] = (_Float16)(hv - (float)hh);
      if constexpr (ISL2) {
        if (t == 63) out[row * 64 + n0 + lr] = hv;
      }
    }
}

__global__ __launch_bounds__(256, 2) void cfc_persist(Params p) {
  __shared__ _Float16 BL[32768];   // 64 KB B-tile, read-only after startup
  const int bid = blockIdx.x;
  const int wv = threadIdx.x >> 6;
  const int lane = threadIdx.x & 63;
  const int lr = lane & 15;

  // startup: zero h ping-pong planes (ws poisoned 0xAA each call)
  for (int i = bid * 256 + threadIdx.x; i < p.hzN; i += 400 * 256) p.hz[i] = 0u;

  if (bid < 128) {
    // ===== XG (gate-pair) + XP =====
    const int n0 = (bid & 31) * 16;
    const int gp = (bid >> 5) & 1;
    const int mw = (bid >> 6) * 256 + wv * 64;
    load_b_lds(BL, gp ? p.w0ta : p.w0f1, gp ? p.w0tb : p.w0f2, nullptr, nullptr,
               p.m0, gp ? 0 : 2, 2, 24, 1280, 0, n0);
    const int xtid = bid * 256 + threadIdx.x;          // [0, 32768)
    for (int s = 0; s < 69; ++s) {
      gridbar(p.bar, (unsigned)(s + 1));
      const int t = s - 1;
      if (t >= 0 && t < 64) {
        const _Float16* xh = (t & 1) ? p.xh1 : p.xh0;
        const _Float16* xl = (t & 1) ? p.xl1 : p.xl0;
        float* xacc = (t & 1) ? p.xacc1 : p.xacc0;
        f32x4 acc[4][2] = {};
        kloop<2, 24, 4, 24>(BL, xh, xl, 768, nullptr, nullptr, 0, mw, acc);
        store_pair<2, 4>(xacc, 2048, 512, gp * 2, mw, n0, acc);
      }
      const int t2 = s;
      if (t2 < 64) {
        _Float16* xh = (t2 & 1) ? p.xh1 : p.xh0;
        _Float16* xl = (t2 & 1) ? p.xl1 : p.xl0;
        for (int i = xtid; i < 49152; i += 32768) {    // 512 rows * 96 8-groups
          const int m = i / 96;
          const int k = (i - m * 96) * 8;
          const float* src = (k < 256) ? (p.base + ((long)m * 64 + t2) * 256 + k)
                                       : (p.visual + ((long)m * 64 + t2) * 512 + (k - 256));
          const f32x4* q = (const f32x4*)src;
          f32x4 v0 = q[0], v1 = q[1];
          half8 hh, ll;
#pragma unroll
          for (int j = 0; j < 4; ++j) {
            _Float16 a = (_Float16)v0[j]; hh[j] = a;     ll[j]     = (_Float16)(v0[j] - (float)a);
            _Float16 c = (_Float16)v1[j]; hh[j + 4] = c; ll[j + 4] = (_Float16)(v1[j] - (float)c);
          }
          *(half8*)(xh + (long)m * 768 + k) = hh;
          *(half8*)(xl + (long)m * 768 + k) = ll;
        }
      }
    }
  } else if (bid < 256) {
    // ===== R0: L0 recurrent (full-gate) =====
    const int sub = bid - 128;
    const int n0 = (sub & 31) * 16;
    const int mw = (sub >> 5) * 128 + wv * 32;
    load_b_lds(BL, p.w0f1, p.w0f2, p.w0ta, p.w0tb, nullptr, 0, 4, 16, 1280, 768, n0);
    const float bf1 = p.b0f1[n0 + lr], bf2 = p.b0f2[n0 + lr];
    const float bta = p.b0ta[n0 + lr], btb = p.b0tb[n0 + lr];
    for (int s = 0; s < 69; ++s) {
      gridbar(p.bar, (unsigned)(s + 1));
      const int t = s - 2;
      if (t < 0 || t >= 64) continue;
      const int pi = (t - 1) & 1;
      const _Float16* ph = pi ? p.h0h1 : p.h0h0;
      const _Float16* pl = pi ? p.h0l1 : p.h0l0;
      _Float16* oh = (t & 1) ? p.h0h1 : p.h0h0;
      _Float16* ol = (t & 1) ? p.h0l1 : p.h0l0;
      const float* xacc = (t & 1) ? p.xacc1 : p.xacc0;
      f32x4 acc[2][4] = {};
      kloop<4, 16, 2, 16>(BL, ph, pl, 512, nullptr, nullptr, 0, mw, acc);
      epi_full<2, 512, true, false>(xacc, 2048, 512, mw, n0, bf1, bf2, bta, btb,
                                    oh, ol, nullptr, t, acc);
    }
  } else if (bid < 320) {
    // ===== R1x: L1 h0-part (gate-pair) =====
    const int sub = bid - 256;
    const int n0 = (sub & 15) * 16;
    const int gp = (sub >> 4) & 1;
    const int mw = (sub >> 5) * 256 + wv * 64;
    load_b_lds(BL, gp ? p.w1ta : p.w1f1, gp ? p.w1tb : p.w1f2, nullptr, nullptr,
               p.m1, gp ? 0 : 2, 2, 16, 768, 0, n0);
    for (int s = 0; s < 69; ++s) {
      gridbar(p.bar, (unsigned)(s + 1));
      const int t = s - 3;
      if (t < 0 || t >= 64) continue;
      const _Float16* ph = (t & 1) ? p.h0h1 : p.h0h0;   // h0(t)
      const _Float16* pl = (t & 1) ? p.h0l1 : p.h0l0;
      float* r1acc = (t & 1) ? p.r1acc1 : p.r1acc0;
      f32x4 acc[4][2] = {};
      kloop<2, 16, 4, 16>(BL, ph, pl, 512, nullptr, nullptr, 0, mw, acc);
      store_pair<2, 4>(r1acc, 1024, 256, gp * 2, mw, n0, acc);
    }
  } else if (bid < 384) {
    // ===== R1r: L1 recurrent (full-gate) =====
    const int sub = bid - 320;
    const int n0 = (sub & 15) * 16;
    const int mw = (sub >> 4) * 128 + wv * 32;
    load_b_lds(BL, p.w1f1, p.w1f2, p.w1ta, p.w1tb, nullptr, 0, 4, 8, 768, 512, n0);
    const float bf1 = p.b1f1[n0 + lr], bf2 = p.b1f2[n0 + lr];
    const float bta = p.b1ta[n0 + lr], btb = p.b1tb[n0 + lr];
    for (int s = 0; s < 69; ++s) {
      gridbar(p.bar, (unsigned)(s + 1));
      const int t = s - 4;
      if (t < 0 || t >= 64) continue;
      const int pi = (t - 1) & 1;
      const _Float16* ph = pi ? p.h1h1 : p.h1h0;        // h1(t-1)
      const _Float16* pl = pi ? p.h1l1 : p.h1l0;
      _Float16* oh = (t & 1) ? p.h1h1 : p.h1h0;
      _Float16* ol = (t & 1) ? p.h1l1 : p.h1l0;
      const float* pre = (t & 1) ? p.r1acc1 : p.r1acc0;
      f32x4 acc[2][4] = {};
      kloop<4, 8, 2, 8>(BL, ph, pl, 256, nullptr, nullptr, 0, mw, acc);
      epi_full<2, 256, true, false>(pre, 1024, 256, mw, n0, bf1, bf2, bta, btb,
                                    oh, ol, nullptr, t, acc);
    }
  } else {
    // ===== L2: full layer (full-gate) =====
    const int sub = bid - 384;
    const int n0 = (sub & 3) * 16;
    const int mw = (sub >> 2) * 128 + wv * 32;
    load_b_lds(BL, p.w2f1, p.w2f2, p.w2ta, p.w2tb, p.m2, 2, 4, 10, 320, 0, n0);
    const float bf1 = p.b2f1[n0 + lr], bf2 = p.b2f2[n0 + lr];
    const float bta = p.b2ta[n0 + lr], btb = p.b2tb[n0 + lr];
    for (int s = 0; s < 69; ++s) {
      gridbar(p.bar, (unsigned)(s + 1));
      const int t = s - 5;
      if (t < 0 || t >= 64) continue;
      const _Float16* ph = (t & 1) ? p.h1h1 : p.h1h0;   // h1(t)
      const _Float16* pl = (t & 1) ? p.h1l1 : p.h1l0;
      const int pi = (t - 1) & 1;
      const _Float16* qh = pi ? p.h2h1 : p.h2h0;        // h2(t-1)
      const _Float16* ql = pi ? p.h2l1 : p.h2l0;
      _Float16* oh = (t & 1) ? p.h2h1 : p.h2h0;
      _Float16* ol = (t & 1) ? p.h2l1 : p.h2l0;
      f32x4 acc[2][4] = {};
      kloop<4, 10, 2, 8>(BL, ph, pl, 256, qh, ql, 64, mw, acc);
      epi_full<2, 64, false, true>(nullptr, 0, 0, mw, n0, bf1, bf2, bta, btb,
                                   oh, ol, p.out, t, acc);
    }
  }
}

__global__ void zero_bar(unsigned* __restrict__ b, int n) {
  int i = blockIdx.x * 256 + threadIdx.x;
  if (i < n) {
    const int slot = i >> 4;
    b[i] = (slot >= 400 && slot < 448 && (i & 15) == 0) ? 0xFFFFFFFFu : 0u;
  }
}

extern "C" void kernel_launch(void* const* d_in, const int* in_sizes, int n_in,
                              void* d_out, int out_size, void* d_ws, size_t ws_size,
                              hipStream_t stream) {
  // ---- workspace layout ----
  _Float16* W = (_Float16*)d_ws;
  _Float16* xh0 = W;                    // 512*768 halfs each
  _Float16* xl0 = xh0 + 393216;
  _Float16* xh1 = xl0 + 393216;
  _Float16* xl1 = xh1 + 393216;
  _Float16* hb  = xl1 + 393216;         // h region (zeroed in-kernel)
  _Float16* h0h0 = hb;            _Float16* h0h1 = h0h0 + 262144;
  _Float16* h0l0 = h0h1 + 262144; _Float16* h0l1 = h0l0 + 262144;
  _Float16* h1h0 = h0l1 + 262144; _Float16* h1h1 = h1h0 + 131072;
  _Float16* h1l0 = h1h1 + 131072; _Float16* h1l1 = h1l0 + 131072;
  _Float16* h2h0 = h1l1 + 131072; _Float16* h2h1 = h2h0 + 32768;
  _Float16* h2l0 = h2h1 + 32768;  _Float16* h2l1 = h2l0 + 32768;
  float* xacc0 = (float*)(h2l1 + 32768);   // 512*2048 fp32 each
  float* xacc1 = xacc0 + 1048576;
  float* r1acc0 = xacc1 + 1048576;         // 512*1024 fp32 each
  float* r1acc1 = r1acc0 + 524288;
  unsigned* bar = (unsigned*)(r1acc1 + 524288);  // 7424 uints; total ws ~19.3 MB

  auto in = [&](int i) { return (const float*)d_in[i]; };

  Params p;
  p.base = in(0); p.visual = in(1);
  p.w0f1 = in(2);  p.b0f1 = in(3);  p.w0f2 = in(4);  p.b0f2 = in(5);
  p.w0ta = in(6);  p.b0ta = in(7);  p.w0tb = in(8);  p.b0tb = in(9);  p.m0 = in(10);
  p.w1f1 = in(11); p.b1f1 = in(12); p.w1f2 = in(13); p.b1f2 = in(14);
  p.w1ta = in(15); p.b1ta = in(16); p.w1tb = in(17); p.b1tb = in(18); p.m1 = in(19);
  p.w2f1 = in(20); p.b2f1 = in(21); p.w2f2 = in(22); p.b2f2 = in(23);
  p.w2ta = in(24); p.b2ta = in(25); p.w2tb = in(26); p.b2tb = in(27); p.m2 = in(28);
  p.xh0 = xh0; p.xl0 = xl0; p.xh1 = xh1; p.xl1 = xl1;
  p.xacc0 = xacc0; p.xacc1 = xacc1;
  p.r1acc0 = r1acc0; p.r1acc1 = r1acc1;
  p.h0h0 = h0h0; p.h0h1 = h0h1; p.h0l0 = h0l0; p.h0l1 = h0l1;
  p.h1h0 = h1h0; p.h1h1 = h1h1; p.h1l0 = h1l0; p.h1l1 = h1l1;
  p.h2h0 = h2h0; p.h2h1 = h2h1; p.h2l0 = h2l0; p.h2l1 = h2l1;
  p.hz = (unsigned*)hb; p.hzN = 1703936 / 2;
  p.bar = bar;
  p.out = (float*)d_out;

  zero_bar<<<29, 256, 0, stream>>>(bar, 7424);
  cfc_persist<<<400, 256, 0, stream>>>(p);
}